// Round 7
// baseline (424.941 us; speedup 1.0000x reference)
//
#include <hip/hip_runtime.h>
#include <hip/hip_bf16.h>

#define NN 50000
#define EE 600000
#define HH 128
#define OUTD 32
#define RR 64
#define BB 16
#define KK 2048   // BB*HH
#define NPB 16    // nodes per fused block (50000 = 16 * 3125 exactly)
#define SC_B ((NN + 1023) / 1024)  // 49 scan chunks

typedef short s16x8 __attribute__((ext_vector_type(8)));
typedef float f32x4 __attribute__((ext_vector_type(4)));
typedef unsigned short ushort_t;
typedef unsigned int uint_t;
typedef __attribute__((address_space(3))) uint_t lds_u32;
typedef const __attribute__((address_space(1))) uint_t glb_u32;

__device__ inline ushort_t f_to_bf16(float f){
    __hip_bfloat16 h = __float2bfloat16(f);
    return *reinterpret_cast<ushort_t*>(&h);
}
__device__ inline uint_t pack_bf16x2(float a, float b){
    return (uint_t)f_to_bf16(a) | ((uint_t)f_to_bf16(b) << 16);
}

__global__ void zero_i32(int* p, int n){
    int i = blockIdx.x*256 + threadIdx.x;
    if (i < n) p[i] = 0;
}

__global__ void hist_kernel(const int* __restrict__ dst, int* counts){
    int e = blockIdx.x*256 + threadIdx.x;
    if (e < EE) atomicAdd(&counts[dst[e]], 1);
}

// ---- hierarchical scan: chunk totals -> scan totals -> final ----
__global__ void scan_part(const int* __restrict__ counts, int* __restrict__ tot){
    int b = blockIdx.x, t = threadIdx.x;
    int i0 = b*1024 + t*4;
    int s = 0;
    if (i0 + 3 < NN){
        int4 v = *reinterpret_cast<const int4*>(&counts[i0]);
        s = v.x + v.y + v.z + v.w;
    } else {
        for (int j = 0; j < 4; j++) if (i0 + j < NN) s += counts[i0 + j];
    }
    #pragma unroll
    for (int off = 32; off; off >>= 1) s += __shfl_xor(s, off, 64);
    __shared__ int ws[4];
    if ((t & 63) == 0) ws[t >> 6] = s;
    __syncthreads();
    if (t == 0) tot[b] = ws[0] + ws[1] + ws[2] + ws[3];
}

__global__ void scan_tot(int* tot){  // 1 block, 64 threads (SC_B <= 64)
    int t = threadIdx.x;
    int v = (t < SC_B) ? tot[t] : 0;
    int x = v;
    #pragma unroll
    for (int off = 1; off < 64; off <<= 1){
        int y = __shfl_up(x, off, 64);
        if (t >= off) x += y;
    }
    if (t < SC_B) tot[t] = x - v;  // exclusive base per chunk
}

__global__ void scan_final(const int* __restrict__ counts, const int* __restrict__ tot,
                           int* __restrict__ offsets, int* __restrict__ cursor){
    int b = blockIdx.x, t = threadIdx.x, lane = t & 63, wv = t >> 6;
    int i0 = b*1024 + t*4;
    int v[4]; int s = 0;
    #pragma unroll
    for (int j = 0; j < 4; j++){ v[j] = (i0 + j < NN) ? counts[i0 + j] : 0; s += v[j]; }
    int x = s;
    #pragma unroll
    for (int off = 1; off < 64; off <<= 1){
        int y = __shfl_up(x, off, 64);
        if (lane >= off) x += y;
    }
    __shared__ int ws[4];
    if (lane == 63) ws[wv] = x;
    __syncthreads();
    int pre = tot[b];
    for (int i = 0; i < wv; i++) pre += ws[i];
    int run = pre + x - s;  // exclusive start of this thread's 4 elems
    #pragma unroll
    for (int j = 0; j < 4; j++){
        if (i0 + j < NN){
            cursor[i0 + j] = run;
            offsets[i0 + j + 1] = run + v[j];
        }
        run += v[j];
    }
    if (b == 0 && t == 0) offsets[0] = 0;
}

// scatter edge payload sorted by dst: meta[r] = {src, etype, norm_bits, 0}
__global__ void scatter_kernel(const int* __restrict__ dst, const int* __restrict__ src,
                               const int* __restrict__ etype, const float* __restrict__ norm,
                               int* cursor, int4* __restrict__ meta){
    int e = blockIdx.x*256 + threadIdx.x;
    if (e >= EE) return;
    int d = dst[e];
    int r = atomicAdd(&cursor[d], 1);
    int4 m;
    m.x = src[e];
    m.y = etype[e];
    m.z = __float_as_int(norm[e]);
    m.w = 0;
    meta[r] = m;
}

// transposed bf16 weights: Wt1[o][k] = V1[k][o] (k = b*H+i), Wt2[o][k] = V2[k][o]
__global__ void convw_kernel(const float* __restrict__ V1, const float* __restrict__ V2,
                             ushort_t* __restrict__ Wt1, ushort_t* __restrict__ Wt2){
    int i = blockIdx.x*256 + threadIdx.x;
    if (i < HH*KK){
        int o = i / KK, k = i % KK;
        Wt1[i] = f_to_bf16(V1[(size_t)k*HH + o]);
    } else {
        int j = i - HH*KK;
        if (j < OUTD*KK){
            int o = j / KK, k = j % KK;
            Wt2[j] = f_to_bf16(V2[(size_t)k*OUTD + o]);
        }
    }
}

__global__ void conv_emb(const float* __restrict__ emb, ushort_t* __restrict__ xb){
    int i = blockIdx.x*256 + threadIdx.x;
    if (i < NN*HH/2){
        float2 f = *reinterpret_cast<const float2*>(emb + 2*(size_t)i);
        *reinterpret_cast<uint_t*>(xb + 2*(size_t)i) = pack_bf16x2(f.x, f.y);
    }
}

// MFMA-based aggregation: for a node, agg[16 bases][128 feats] =
//   Wgt(16 x 32 edges) x X(32 edges x 128 feats), chunked K=32 edges.
// 8 waves/block, 2 nodes/wave (NPB=16). Per chunk: 8 width-16 LDS-DMAs stage
// 32 x-rows into the wave-private 8KB tile; A-frag = per-edge weights
// (comp[et][b]*norm, bf16, zero-padded); B-frags via strided ds_read_u16.
// After gather: barrier, x-tile LDS re-aliased as 16x4KB swizzled agg tile,
// then the dense GEMM vs Wt.
template<int NOUT, bool RELU, bool OUT_BF16>
__global__ __launch_bounds__(512, 4) void fused_layer(
    const ushort_t* __restrict__ xin, const int4* __restrict__ meta,
    const int* __restrict__ offsets, const float* __restrict__ comp,
    const ushort_t* __restrict__ Wt, const float* __restrict__ bias,
    void* __restrict__ yout)
{
    __shared__ __align__(16) char ldsB[NPB * 4096];   // x-tiles (8 x 8KB) | agg (16 x 4KB)
    __shared__ float compL[RR * BB];                  // 4KB

    int tid = threadIdx.x;
    int w = tid >> 6, lane = tid & 63;
    int v0 = blockIdx.x * NPB;
    int lane15 = lane & 15;

    compL[tid] = comp[tid];
    compL[tid + 512] = comp[tid + 512];
    __syncthreads();

    char* xt = ldsB + w * 8192;         // wave-private 8KB x-tile [32 rows][256B]
    f32x4 acc[2][8];
    #pragma unroll
    for (int h2 = 0; h2 < 2; h2++)
        #pragma unroll
        for (int c = 0; c < 8; c++)
            #pragma unroll
            for (int j = 0; j < 4; j++) acc[h2][c][j] = 0.f;

    int colel = lane15 * 8;             // element offset within x row for DMA source

    #pragma unroll 2
    for (int half = 0; half < 2; ++half){
        int v = v0 + w*2 + half;
        int p0 = offsets[v];
        int dd = offsets[v+1] - p0;
        for (int c0 = 0; c0 < dd; c0 += 32){
            int nc = min(32, dd - c0);
            int4 mv = meta[p0 + c0 + min(lane, nc - 1)];   // lane k: meta of edge k
            // stage 32 rows: DMA i covers rows 4i..4i+3; lane -> row 4i+(lane>>4)
            #pragma unroll
            for (int i = 0; i < 8; ++i){
                int er = 4*i + (lane >> 4);
                int sr = __shfl(mv.x, min(er, nc - 1), 64);
                const ushort_t* gp = xin + (size_t)sr*HH + colel;
                __builtin_amdgcn_global_load_lds((glb_u32*)gp, (lds_u32*)(xt + i*1024),
                                                 16, 0, 0);
            }
            // A-frag: lane holds Wgt[m=lane15][k=(lane>>4)*8+j] (bf16), 0 for pads
            s16x8 a;
            #pragma unroll
            for (int j = 0; j < 8; ++j){
                int ke = (lane >> 4)*8 + j;
                int et   = __shfl(mv.y, ke, 64);
                float nw = __int_as_float(__shfl(mv.z, ke, 64));
                float wj = (ke < nc) ? compL[et*BB + lane15] * nw : 0.f;
                a[j] = (short)f_to_bf16(wj);
            }
            asm volatile("s_waitcnt vmcnt(0)" ::: "memory");
            __builtin_amdgcn_sched_barrier(0);
            // 8 col-tiles: B[k][n] = xtile[k][c*16 + n]
            #pragma unroll
            for (int c = 0; c < 8; ++c){
                s16x8 bfr;
                #pragma unroll
                for (int j = 0; j < 8; ++j){
                    bfr[j] = (short)*reinterpret_cast<const ushort_t*>(
                        xt + ((lane >> 4)*8 + j)*256 + c*32 + lane15*2);
                }
                acc[half][c] = __builtin_amdgcn_mfma_f32_16x16x32_bf16(
                    a, bfr, acc[half][c], 0, 0, 0);
            }
        }
    }

    __syncthreads();   // all gathers done; x-tiles dead -> re-alias as agg tile

    // write agg rows: D layout col=lane&15 (feat), row=(lane>>4)*4+r (basis)
    #pragma unroll 2
    for (int half = 0; half < 2; ++half){
        int row = w*2 + half;
        int swz = (row & 7) << 4;
        char* rowp = ldsB + row*4096;
        #pragma unroll
        for (int c = 0; c < 8; ++c)
            #pragma unroll
            for (int r = 0; r < 4; ++r){
                int elem = ((lane >> 4)*4 + r)*128 + c*16 + lane15;
                *reinterpret_cast<ushort_t*>(rowp + ((elem*2) ^ swz)) =
                    f_to_bf16(acc[half][c][r]);
            }
    }
    __syncthreads();

    // ---- dense GEMM: out[node][:] = agg[node][:] @ Wt^T + bias ----
    int kc = (lane >> 4) * 8;
    int rswz = (lane15 & 7) << 4;
    float* partS = reinterpret_cast<float*>(ldsB);

    if (NOUT == HH){
        // wave w -> col-tile w (16 cols), full K=2048
        f32x4 acc2;
        #pragma unroll
        for (int j = 0; j < 4; j++) acc2[j] = 0.f;
        const ushort_t* wrow = Wt + (size_t)(w*16 + lane15)*KK + kc;
        #pragma unroll 4
        for (int k = 0; k < KK; k += 32){
            s16x8 a = *reinterpret_cast<const s16x8*>(
                ldsB + lane15*4096 + (((k + kc)*2) ^ rswz));
            s16x8 b = *reinterpret_cast<const s16x8*>(wrow + k);
            acc2 = __builtin_amdgcn_mfma_f32_16x16x32_bf16(a, b, acc2, 0, 0, 0);
        }
        int col = w*16 + lane15;
        float bv = bias[col];
        #pragma unroll
        for (int r = 0; r < 4; r++){
            int row = (lane >> 4)*4 + r;
            float val = acc2[r] + bv;
            if (RELU) val = fmaxf(val, 0.f);
            if (OUT_BF16)
                reinterpret_cast<ushort_t*>(yout)[(size_t)(v0 + row)*NOUT + col] = f_to_bf16(val);
            else
                reinterpret_cast<float*>(yout)[(size_t)(v0 + row)*NOUT + col] = val;
        }
    } else {
        // 2 col-tiles x 4 K-parts (K=512 each), reduce via LDS
        int nt = w & 1, kp = w >> 1;
        f32x4 acc2;
        #pragma unroll
        for (int j = 0; j < 4; j++) acc2[j] = 0.f;
        int kbeg = kp * 512;
        const ushort_t* wrow = Wt + (size_t)(nt*16 + lane15)*KK + kbeg + kc;
        #pragma unroll
        for (int k = 0; k < 512; k += 32){
            s16x8 a = *reinterpret_cast<const s16x8*>(
                ldsB + lane15*4096 + (((kbeg + k + kc)*2) ^ rswz));
            s16x8 b = *reinterpret_cast<const s16x8*>(wrow + k);
            acc2 = __builtin_amdgcn_mfma_f32_16x16x32_bf16(a, b, acc2, 0, 0, 0);
        }
        __syncthreads();
        #pragma unroll
        for (int r = 0; r < 4; r++){
            int idx = ((lane >> 4)*4 + r)*16 + lane15;
            partS[w*256 + idx] = acc2[r];   // w == kp*2 + nt
        }
        __syncthreads();
        {
            int nt2 = tid >> 8, idx = tid & 255;
            int col = nt2*16 + (idx & 15);
            float s = bias[col];
            #pragma unroll
            for (int kp2 = 0; kp2 < 4; kp2++) s += partS[(kp2*2 + nt2)*256 + idx];
            if (RELU) s = fmaxf(s, 0.f);
            int node = v0 + (idx >> 4);
            if (OUT_BF16)
                reinterpret_cast<ushort_t*>(yout)[(size_t)node*NOUT + col] = f_to_bf16(s);
            else
                reinterpret_cast<float*>(yout)[(size_t)node*NOUT + col] = s;
        }
    }
}

extern "C" void kernel_launch(void* const* d_in, const int* in_sizes, int n_in,
                              void* d_out, int out_size, void* d_ws, size_t ws_size,
                              hipStream_t stream){
    const int*   src   = (const int*)d_in[0];
    const int*   dst   = (const int*)d_in[1];
    const int*   etype = (const int*)d_in[2];
    const float* norm  = (const float*)d_in[3];
    const float* emb   = (const float*)d_in[4];
    const float* V1    = (const float*)d_in[5];
    const float* comp1 = (const float*)d_in[6];
    const float* bias1 = (const float*)d_in[7];
    const float* V2    = (const float*)d_in[8];
    const float* comp2 = (const float*)d_in[9];
    const float* bias2 = (const float*)d_in[10];
    float* out = (float*)d_out;

    char* w = (char*)d_ws;
    auto alloc = [&](size_t bytes) -> char* {
        char* p = w; w += (bytes + 255) & ~(size_t)255; return p;
    };
    int*      offsets = (int*)alloc((NN + 1) * 4);
    int*      counts  = (int*)alloc(NN * 4);
    int*      cursor  = (int*)alloc(NN * 4);
    int*      tot     = (int*)alloc(SC_B * 4);
    int4*     meta    = (int4*)alloc((size_t)EE * 16);
    ushort_t* Wt1     = (ushort_t*)alloc((size_t)HH * KK * 2);
    ushort_t* Wt2     = (ushort_t*)alloc((size_t)OUTD * KK * 2);
    ushort_t* xb      = (ushort_t*)alloc((size_t)NN * HH * 2);
    ushort_t* h       = (ushort_t*)alloc((size_t)NN * HH * 2);

    // CSR build + payload sort + weight/emb conversion
    zero_i32<<<(NN + 255)/256, 256, 0, stream>>>(counts, NN);
    hist_kernel<<<(EE + 255)/256, 256, 0, stream>>>(dst, counts);
    scan_part<<<SC_B, 256, 0, stream>>>(counts, tot);
    scan_tot<<<1, 64, 0, stream>>>(tot);
    scan_final<<<SC_B, 256, 0, stream>>>(counts, tot, offsets, cursor);
    scatter_kernel<<<(EE + 255)/256, 256, 0, stream>>>(dst, src, etype, norm, cursor, meta);
    convw_kernel<<<((HH + OUTD)*KK + 255)/256, 256, 0, stream>>>(V1, V2, Wt1, Wt2);
    conv_emb<<<(NN*HH/2 + 255)/256, 256, 0, stream>>>(emb, xb);

    int nblocks = NN / NPB;  // 3125 exact
    // layer 1: xb (bf16) -> h (bf16, relu)
    fused_layer<HH, true, true><<<nblocks, 512, 0, stream>>>(
        xb, meta, offsets, comp1, Wt1, bias1, h);
    // layer 2: h (bf16) -> out (f32)
    fused_layer<OUTD, false, false><<<nblocks, 512, 0, stream>>>(
        h, meta, offsets, comp2, Wt2, bias2, out);
}